// Round 5
// baseline (570.188 us; speedup 1.0000x reference)
//
#include <hip/hip_runtime.h>
#include <hip/hip_fp16.h>
#include <cstdint>
#include <cstddef>

#define N_NODES 50000
#define N_EDGES 1600000
#define NEG_SLOPE 0.2f
#define GAT_EPS 1e-16f

// ---------------- single-block exclusive scan, 4 elems/thread ----------------

__global__ void k_scan(const int* __restrict__ cnt, int* __restrict__ row_start) {
    __shared__ int wsum[16];
    __shared__ int wpre[16];
    __shared__ int total;
    __shared__ int chunk_base;
    int t = threadIdx.x;
    int lane = t & 63, wid = t >> 6;
    if (t == 0) chunk_base = 0;
    __syncthreads();
    for (int base = 0; base < N_NODES; base += 4096) {
        int i0 = base + t * 4;
        int v0 = (i0 + 0 < N_NODES) ? cnt[i0 + 0] : 0;
        int v1 = (i0 + 1 < N_NODES) ? cnt[i0 + 1] : 0;
        int v2 = (i0 + 2 < N_NODES) ? cnt[i0 + 2] : 0;
        int v3 = (i0 + 3 < N_NODES) ? cnt[i0 + 3] : 0;
        int s0 = v0, s1 = s0 + v1, s2 = s1 + v2, s3 = s2 + v3;
        int x = s3;
#pragma unroll
        for (int off = 1; off < 64; off <<= 1) {
            int y = __shfl_up(x, off, 64);
            if (lane >= off) x += y;
        }
        if (lane == 63) wsum[wid] = x;
        __syncthreads();
        if (t < 16) {
            int w = wsum[t];
            int xx = w;
#pragma unroll
            for (int off = 1; off < 16; off <<= 1) {
                int y = __shfl_up(xx, off, 16);
                if (t >= off) xx += y;
            }
            wpre[t] = xx - w;
            if (t == 15) total = xx;
        }
        __syncthreads();
        int excl = chunk_base + wpre[wid] + (x - s3);
        if (i0 + 3 < N_NODES) {
            ((int4*)row_start)[i0 >> 2] = make_int4(excl, excl + s0, excl + s1, excl + s2);
        } else {
            if (i0 + 0 < N_NODES) row_start[i0 + 0] = excl;
            if (i0 + 1 < N_NODES) row_start[i0 + 1] = excl + s0;
            if (i0 + 2 < N_NODES) row_start[i0 + 2] = excl + s1;
        }
        __syncthreads();
        if (t == 0) chunk_base += total;
        __syncthreads();
    }
    if (t == 0) row_start[N_NODES] = chunk_base;
}

// scatter + layer-1 edge weights + softmax denominators (atomic)
__global__ void k_scatter_w(const int* __restrict__ ei, const int* __restrict__ row_start,
                            int* __restrict__ fill, int* __restrict__ csr_src,
                            const float* __restrict__ a_src1, const float* __restrict__ a_dst1,
                            float* __restrict__ w1_csr, float* __restrict__ den1) {
    int i = blockIdx.x * blockDim.x + threadIdx.x;
    if (i >= N_EDGES) return;
    int s = ei[i];
    int d = ei[N_EDGES + i];
    int pos = atomicAdd(&fill[d], 1);
    int slot = row_start[d] + pos;
    csr_src[slot] = s;
    float2 as = ((const float2*)a_src1)[s];
    float2 ad = ((const float2*)a_dst1)[d];
    float e0 = as.x + ad.x; e0 = (e0 >= 0.f) ? e0 : NEG_SLOPE * e0;
    float e1 = as.y + ad.y; e1 = (e1 >= 0.f) ? e1 : NEG_SLOPE * e1;
    float w0 = expf(e0), w1 = expf(e1);
    ((float2*)w1_csr)[slot] = make_float2(w0, w1);
    atomicAdd(&den1[d * 2 + 0], w0);
    atomicAdd(&den1[d * 2 + 1], w1);
}

// ---------------- Layer 1 GEMM (fp16 out) + attention scalars + fused edge count ----------------

__global__ __launch_bounds__(256) void k_gemm1c(
    const float* __restrict__ x, const float* __restrict__ W1,
    const float* __restrict__ att_src, const float* __restrict__ att_dst,
    __half* __restrict__ h1, float* __restrict__ a_src, float* __restrict__ a_dst,
    const int* __restrict__ ei, int* __restrict__ cnt) {
    __shared__ float wl[128 * 128];
    __shared__ float xl[32 * 128];
    int t = threadIdx.x;
    int node0 = blockIdx.x * 32;
    {
        const float4* Wv = (const float4*)W1;
        float4* wlv = (float4*)wl;
        for (int j = t; j < 128 * 128 / 4; j += 256) wlv[j] = Wv[j];
    }
    {
        float4* xlv = (float4*)xl;
        for (int j = t; j < 32 * 128 / 4; j += 256) {
            int n = j >> 5;
            int rem = j & 31;
            int gn = node0 + n;
            float4 v = make_float4(0.f, 0.f, 0.f, 0.f);
            if (gn < N_NODES) v = ((const float4*)x)[(size_t)gn * 32 + rem];
            xlv[j] = v;
        }
    }
    __syncthreads();
    int c = t & 127;
    int nb = t >> 7;
    float acc[16];
#pragma unroll
    for (int n = 0; n < 16; ++n) acc[n] = 0.f;
    for (int k4 = 0; k4 < 32; ++k4) {
        int k = k4 * 4;
        float w0 = wl[(k + 0) * 128 + c];
        float w1_ = wl[(k + 1) * 128 + c];
        float w2_ = wl[(k + 2) * 128 + c];
        float w3_ = wl[(k + 3) * 128 + c];
#pragma unroll
        for (int n = 0; n < 16; ++n) {
            float4 xv = ((const float4*)(xl + (nb * 16 + n) * 128))[k4];
            acc[n] += w0 * xv.x + w1_ * xv.y + w2_ * xv.z + w3_ * xv.w;
        }
    }
    float as_c = att_src[c];
    float ad_c = att_dst[c];
    int lane = t & 63;
    int head = (c >= 64) ? 1 : 0;
#pragma unroll
    for (int n = 0; n < 16; ++n) {
        int gn = node0 + nb * 16 + n;
        float hv = acc[n];
        float ps = hv * as_c;
        float pd = hv * ad_c;
#pragma unroll
        for (int off = 32; off >= 1; off >>= 1) {
            ps += __shfl_xor(ps, off, 64);
            pd += __shfl_xor(pd, off, 64);
        }
        if (gn < N_NODES) {
            h1[(size_t)gn * 128 + c] = __float2half(hv);
            if (lane == 0) {
                a_src[gn * 2 + head] = ps;
                a_dst[gn * 2 + head] = pd;
            }
        }
    }
    // fused edge counting: this block's 1024-edge chunk
    int e0 = blockIdx.x * 1024;
    int e1 = e0 + 1024; if (e1 > N_EDGES) e1 = N_EDGES;
    for (int e = e0 + t; e < e1; e += 256)
        atomicAdd(&cnt[ei[N_EDGES + e]], 1);
}

// ---------------- Layer 1 aggregation + ELU + fused layer-2 GEMM ----------------
// One wave per destination node; lane owns channels 2*lane, 2*lane+1.

__global__ __launch_bounds__(256) void k_agg1f(
    const int* __restrict__ row_start, const int* __restrict__ csr_src,
    const __half* __restrict__ h1, const float* __restrict__ w1_csr,
    const float* __restrict__ den1, const float* __restrict__ b1,
    const float* __restrict__ W2,
    const float* __restrict__ att_src2, const float* __restrict__ att_dst2,
    float* __restrict__ h2, float* __restrict__ as2, float* __restrict__ ad2) {
    __shared__ float w2t[16 * 132];     // W2^T, row padded to 132
    __shared__ float rows[4][128];
    int t = threadIdx.x;
    for (int i = t; i < 2048; i += 256) {
        int k = i >> 4, j = i & 15;
        w2t[j * 132 + k] = W2[i];
    }
    __syncthreads();   // only barrier: staging done before any wave needs w2t
    int wv = t >> 6, lane = t & 63;
    int d = blockIdx.x * 4 + wv;
    int row = row_start[d], end = row_start[d + 1];
    const float2* w1v = (const float2*)w1_csr;
    int head = lane >> 5;
    float2 dn = ((const float2*)den1)[d];
    float inv = 1.f / ((head ? dn.y : dn.x) + GAT_EPS);
    // weighted gather-accumulate, 4 edges in flight
    float accx = 0.f, accy = 0.f;
    int i = row;
    for (; i + 4 <= end; i += 4) {
        int s0 = csr_src[i], s1 = csr_src[i + 1], s2 = csr_src[i + 2], s3 = csr_src[i + 3];
        float2 w0 = w1v[i], w1e = w1v[i + 1], w2e = w1v[i + 2], w3e = w1v[i + 3];
        float2 h0 = __half22float2(((const __half2*)(h1 + (size_t)s0 * 128))[lane]);
        float2 hb = __half22float2(((const __half2*)(h1 + (size_t)s1 * 128))[lane]);
        float2 hc = __half22float2(((const __half2*)(h1 + (size_t)s2 * 128))[lane]);
        float2 hd = __half22float2(((const __half2*)(h1 + (size_t)s3 * 128))[lane]);
        float wa = head ? w0.y : w0.x;
        float wb = head ? w1e.y : w1e.x;
        float wc = head ? w2e.y : w2e.x;
        float wd = head ? w3e.y : w3e.x;
        accx += wa * h0.x + wb * hb.x + wc * hc.x + wd * hd.x;
        accy += wa * h0.y + wb * hb.y + wc * hc.y + wd * hd.y;
    }
    for (; i < end; ++i) {
        int s = csr_src[i];
        float2 w0 = w1v[i];
        float2 ha = __half22float2(((const __half2*)(h1 + (size_t)s * 128))[lane]);
        float wa = head ? w0.y : w0.x;
        accx += wa * ha.x; accy += wa * ha.y;
    }
    accx *= inv; accy *= inv;
    int c0 = lane * 2;
    float ox = accx + b1[c0], oy = accy + b1[c0 + 1];
    ox = (ox > 0.f) ? ox : expm1f(ox);   // ELU
    oy = (oy > 0.f) ? oy : expm1f(oy);
    rows[wv][c0] = ox;
    rows[wv][c0 + 1] = oy;
    // rows[wv] written & read by the same wave — no barrier needed
    int j = lane & 15, q = lane >> 4;
    const float* r = rows[wv];
    const float* wt = &w2t[j * 132];
    int k0 = q * 32;
    float acc2 = 0.f;
#pragma unroll
    for (int kk = 0; kk < 32; kk += 4) {
        float4 rv = *(const float4*)(r + k0 + kk);
        float4 w4 = *(const float4*)(wt + k0 + kk);
        acc2 += rv.x * w4.x + rv.y * w4.y + rv.z * w4.z + rv.w * w4.w;
    }
    acc2 += __shfl_xor(acc2, 16, 64);
    acc2 += __shfl_xor(acc2, 32, 64);
    if (lane < 16) {
        h2[(size_t)d * 16 + j] = acc2;
        float ps = acc2 * att_src2[j];
        float pd = acc2 * att_dst2[j];
#pragma unroll
        for (int off = 8; off >= 1; off >>= 1) {
            ps += __shfl_xor(ps, off, 64);
            pd += __shfl_xor(pd, off, 64);
        }
        if (lane == 0) { as2[d] = ps; ad2[d] = pd; }
    }
}

// ---------------- Layer 2 aggregation + bias + softmax: one wave per node ----------------
// Phase A: exp once per edge (edge-parallel). Phase B: shfl-broadcast w,s; 4 edges/iter.

__global__ __launch_bounds__(256) void k_agg2(
    const int* __restrict__ row_start, const int* __restrict__ csr_src,
    const float* __restrict__ h2, const float* __restrict__ as2,
    const float* __restrict__ ad2, const float* __restrict__ b2,
    float* __restrict__ out) {
    int t = threadIdx.x;
    int wv = t >> 6, lane = t & 63;
    int d = blockIdx.x * 4 + wv;
    int row = row_start[d], end = row_start[d + 1];
    float ad = ad2[d];
    int c = lane & 15, q = lane >> 4;
    float den = 0.f, acc = 0.f;
    for (int base = row; base < end; base += 64) {
        int idx = base + lane;
        float w = 0.f; int s = 0;
        if (idx < end) {
            s = csr_src[idx];
            float e = as2[s] + ad;
            e = (e >= 0.f) ? e : NEG_SLOPE * e;
            w = expf(e);
        }
        den += w;
        int m = end - base; if (m > 64) m = 64;
        for (int jj = 0; jj < m; jj += 4) {
            float wj = __shfl(w, jj + q, 64);
            int sj = __shfl(s, jj + q, 64);
            acc += wj * h2[(size_t)sj * 16 + c];
        }
    }
#pragma unroll
    for (int off = 32; off >= 1; off >>= 1) den += __shfl_xor(den, off, 64);
    acc += __shfl_xor(acc, 16, 64);
    acc += __shfl_xor(acc, 32, 64);
    float v = acc / (den + GAT_EPS) + b2[c];
    float mmax = v;
#pragma unroll
    for (int off = 8; off >= 1; off >>= 1) mmax = fmaxf(mmax, __shfl_xor(mmax, off, 16));
    float ex = expf(v - mmax);
    float sum = ex;
#pragma unroll
    for (int off = 8; off >= 1; off >>= 1) sum += __shfl_xor(sum, off, 16);
    if (lane < 16) out[(size_t)d * 16 + c] = ex / sum;
}

// ---------------- launch ----------------

extern "C" void kernel_launch(void* const* d_in, const int* in_sizes, int n_in,
                              void* d_out, int out_size, void* d_ws, size_t ws_size,
                              hipStream_t stream) {
    const float* x        = (const float*)d_in[0];
    const float* W1       = (const float*)d_in[1];
    const float* att_src1 = (const float*)d_in[2];
    const float* att_dst1 = (const float*)d_in[3];
    const float* b1       = (const float*)d_in[4];
    const float* W2       = (const float*)d_in[5];
    const float* att_src2 = (const float*)d_in[6];
    const float* att_dst2 = (const float*)d_in[7];
    const float* b2       = (const float*)d_in[8];
    const int*   ei       = (const int*)d_in[9];   // [2, E]: src row then dst row

    char* p = (char*)d_ws;
    auto alloc = [&](size_t bytes) {
        char* r = p;
        p += (bytes + 255) & ~(size_t)255;
        return r;
    };
    __half* h1     = (__half*)alloc(sizeof(__half) * (size_t)N_NODES * 128);
    float* h2      = (float*)alloc(sizeof(float) * (size_t)N_NODES * 16);
    float* a_src   = (float*)alloc(sizeof(float) * N_NODES * 2);
    float* a_dst   = (float*)alloc(sizeof(float) * N_NODES * 2);
    float* as2     = (float*)alloc(sizeof(float) * N_NODES);
    float* ad2     = (float*)alloc(sizeof(float) * N_NODES);
    // zero-init region: cnt | fill | den1  (contiguous, one memset)
    int* cnt       = (int*)alloc(sizeof(int) * N_NODES * 2 + sizeof(float) * N_NODES * 2);
    int* fill      = cnt + N_NODES;
    float* den1    = (float*)(cnt + 2 * N_NODES);
    int* row_start = (int*)alloc(sizeof(int) * (N_NODES + 1));
    int* csr_src   = (int*)alloc(sizeof(int) * N_EDGES);
    float* w1_csr  = (float*)alloc(sizeof(float) * (size_t)N_EDGES * 2);

    (void)hipMemsetAsync(cnt, 0, sizeof(int) * N_NODES * 2 + sizeof(float) * N_NODES * 2, stream);
    k_gemm1c<<<(N_NODES + 31) / 32, 256, 0, stream>>>(x, W1, att_src1, att_dst1, h1, a_src, a_dst, ei, cnt);
    k_scan<<<1, 1024, 0, stream>>>(cnt, row_start);
    k_scatter_w<<<(N_EDGES + 255) / 256, 256, 0, stream>>>(ei, row_start, fill, csr_src, a_src, a_dst, w1_csr, den1);
    k_agg1f<<<N_NODES / 4, 256, 0, stream>>>(row_start, csr_src, h1, w1_csr, den1, b1, W2, att_src2, att_dst2, h2, as2, ad2);
    k_agg2<<<N_NODES / 4, 256, 0, stream>>>(row_start, csr_src, h2, as2, ad2, b2, (float*)d_out);
}

// Round 6
// 441.904 us; speedup vs baseline: 1.2903x; 1.2903x over previous
//
#include <hip/hip_runtime.h>
#include <hip/hip_fp16.h>
#include <cstdint>
#include <cstddef>

#define N_NODES 50000
#define N_EDGES 1600000
#define NEG_SLOPE 0.2f
#define GAT_EPS 1e-16f

// ---------------- single-block exclusive scan, 4 elems/thread ----------------

__global__ void k_scan(const int* __restrict__ cnt, int* __restrict__ row_start) {
    __shared__ int wsum[16];
    __shared__ int wpre[16];
    __shared__ int total;
    __shared__ int chunk_base;
    int t = threadIdx.x;
    int lane = t & 63, wid = t >> 6;
    if (t == 0) chunk_base = 0;
    __syncthreads();
    for (int base = 0; base < N_NODES; base += 4096) {
        int i0 = base + t * 4;
        int v0 = (i0 + 0 < N_NODES) ? cnt[i0 + 0] : 0;
        int v1 = (i0 + 1 < N_NODES) ? cnt[i0 + 1] : 0;
        int v2 = (i0 + 2 < N_NODES) ? cnt[i0 + 2] : 0;
        int v3 = (i0 + 3 < N_NODES) ? cnt[i0 + 3] : 0;
        int s0 = v0, s1 = s0 + v1, s2 = s1 + v2, s3 = s2 + v3;
        int x = s3;
#pragma unroll
        for (int off = 1; off < 64; off <<= 1) {
            int y = __shfl_up(x, off, 64);
            if (lane >= off) x += y;
        }
        if (lane == 63) wsum[wid] = x;
        __syncthreads();
        if (t < 16) {
            int w = wsum[t];
            int xx = w;
#pragma unroll
            for (int off = 1; off < 16; off <<= 1) {
                int y = __shfl_up(xx, off, 16);
                if (t >= off) xx += y;
            }
            wpre[t] = xx - w;
            if (t == 15) total = xx;
        }
        __syncthreads();
        int excl = chunk_base + wpre[wid] + (x - s3);
        if (i0 + 3 < N_NODES) {
            ((int4*)row_start)[i0 >> 2] = make_int4(excl, excl + s0, excl + s1, excl + s2);
        } else {
            if (i0 + 0 < N_NODES) row_start[i0 + 0] = excl;
            if (i0 + 1 < N_NODES) row_start[i0 + 1] = excl + s0;
            if (i0 + 2 < N_NODES) row_start[i0 + 2] = excl + s1;
        }
        __syncthreads();
        if (t == 0) chunk_base += total;
        __syncthreads();
    }
    if (t == 0) row_start[N_NODES] = chunk_base;
}

// scatter + layer-1 edge weights (no atomics beyond the slot counter)
__global__ void k_scatter_w(const int* __restrict__ ei, const int* __restrict__ row_start,
                            int* __restrict__ fill, int* __restrict__ csr_src,
                            const float* __restrict__ a_src1, const float* __restrict__ a_dst1,
                            float* __restrict__ w1_csr) {
    int i = blockIdx.x * blockDim.x + threadIdx.x;
    if (i >= N_EDGES) return;
    int s = ei[i];
    int d = ei[N_EDGES + i];
    int pos = atomicAdd(&fill[d], 1);
    int slot = row_start[d] + pos;
    csr_src[slot] = s;
    float2 as = ((const float2*)a_src1)[s];
    float2 ad = ((const float2*)a_dst1)[d];
    float e0 = as.x + ad.x; e0 = (e0 >= 0.f) ? e0 : NEG_SLOPE * e0;
    float e1 = as.y + ad.y; e1 = (e1 >= 0.f) ? e1 : NEG_SLOPE * e1;
    ((float2*)w1_csr)[slot] = make_float2(expf(e0), expf(e1));
}

// ---------------- Layer 1 GEMM (fp16 out) + attention scalars + fused edge count ----------------

__global__ __launch_bounds__(256) void k_gemm1c(
    const float* __restrict__ x, const float* __restrict__ W1,
    const float* __restrict__ att_src, const float* __restrict__ att_dst,
    __half* __restrict__ h1, float* __restrict__ a_src, float* __restrict__ a_dst,
    const int* __restrict__ ei, int* __restrict__ cnt) {
    __shared__ float wl[128 * 128];
    __shared__ float xl[32 * 128];
    int t = threadIdx.x;
    int node0 = blockIdx.x * 32;
    {
        const float4* Wv = (const float4*)W1;
        float4* wlv = (float4*)wl;
        for (int j = t; j < 128 * 128 / 4; j += 256) wlv[j] = Wv[j];
    }
    {
        float4* xlv = (float4*)xl;
        for (int j = t; j < 32 * 128 / 4; j += 256) {
            int n = j >> 5;
            int rem = j & 31;
            int gn = node0 + n;
            float4 v = make_float4(0.f, 0.f, 0.f, 0.f);
            if (gn < N_NODES) v = ((const float4*)x)[(size_t)gn * 32 + rem];
            xlv[j] = v;
        }
    }
    __syncthreads();
    int c = t & 127;
    int nb = t >> 7;
    float acc[16];
#pragma unroll
    for (int n = 0; n < 16; ++n) acc[n] = 0.f;
    for (int k4 = 0; k4 < 32; ++k4) {
        int k = k4 * 4;
        float w0 = wl[(k + 0) * 128 + c];
        float w1_ = wl[(k + 1) * 128 + c];
        float w2_ = wl[(k + 2) * 128 + c];
        float w3_ = wl[(k + 3) * 128 + c];
#pragma unroll
        for (int n = 0; n < 16; ++n) {
            float4 xv = ((const float4*)(xl + (nb * 16 + n) * 128))[k4];
            acc[n] += w0 * xv.x + w1_ * xv.y + w2_ * xv.z + w3_ * xv.w;
        }
    }
    float as_c = att_src[c];
    float ad_c = att_dst[c];
    int lane = t & 63;
    int head = (c >= 64) ? 1 : 0;
#pragma unroll
    for (int n = 0; n < 16; ++n) {
        int gn = node0 + nb * 16 + n;
        float hv = acc[n];
        float ps = hv * as_c;
        float pd = hv * ad_c;
#pragma unroll
        for (int off = 32; off >= 1; off >>= 1) {
            ps += __shfl_xor(ps, off, 64);
            pd += __shfl_xor(pd, off, 64);
        }
        if (gn < N_NODES) {
            h1[(size_t)gn * 128 + c] = __float2half(hv);
            if (lane == 0) {
                a_src[gn * 2 + head] = ps;
                a_dst[gn * 2 + head] = pd;
            }
        }
    }
    // fused edge counting: this block's 1024-edge chunk
    int e0 = blockIdx.x * 1024;
    int e1 = e0 + 1024; if (e1 > N_EDGES) e1 = N_EDGES;
    for (int e = e0 + t; e < e1; e += 256)
        atomicAdd(&cnt[ei[N_EDGES + e]], 1);
}

// ---------------- Layer 1 aggregation + ELU + fused layer-2 GEMM ----------------
// One wave per destination node; lane owns channels 2*lane, 2*lane+1.
// Single loop: weights are broadcast to all lanes, so every lane accumulates
// the full softmax denominator for its head as a byproduct — normalization is
// a constant scale applied after the sum (algebraically identical).

__global__ __launch_bounds__(256) void k_agg1f(
    const int* __restrict__ row_start, const int* __restrict__ csr_src,
    const __half* __restrict__ h1, const float* __restrict__ w1_csr,
    const float* __restrict__ b1, const float* __restrict__ W2,
    const float* __restrict__ att_src2, const float* __restrict__ att_dst2,
    float* __restrict__ h2, float* __restrict__ as2, float* __restrict__ ad2) {
    __shared__ float w2t[16 * 132];     // W2^T, row padded to 132
    __shared__ float rows[4][128];
    int t = threadIdx.x;
    for (int i = t; i < 2048; i += 256) {
        int k = i >> 4, j = i & 15;
        w2t[j * 132 + k] = W2[i];
    }
    __syncthreads();   // only barrier: staging done before any wave needs w2t
    int wv = t >> 6, lane = t & 63;
    int d = blockIdx.x * 4 + wv;
    int row = row_start[d], end = row_start[d + 1];
    const float2* w1v = (const float2*)w1_csr;
    int head = lane >> 5;
    float den = 0.f, accx = 0.f, accy = 0.f;
    int i = row;
    for (; i + 4 <= end; i += 4) {
        int s0 = csr_src[i], s1 = csr_src[i + 1], s2 = csr_src[i + 2], s3 = csr_src[i + 3];
        float2 w0 = w1v[i], w1e = w1v[i + 1], w2e = w1v[i + 2], w3e = w1v[i + 3];
        float2 h0 = __half22float2(((const __half2*)(h1 + (size_t)s0 * 128))[lane]);
        float2 hb = __half22float2(((const __half2*)(h1 + (size_t)s1 * 128))[lane]);
        float2 hc = __half22float2(((const __half2*)(h1 + (size_t)s2 * 128))[lane]);
        float2 hd = __half22float2(((const __half2*)(h1 + (size_t)s3 * 128))[lane]);
        float wa = head ? w0.y : w0.x;
        float wb = head ? w1e.y : w1e.x;
        float wc = head ? w2e.y : w2e.x;
        float wd = head ? w3e.y : w3e.x;
        den += (wa + wb) + (wc + wd);
        accx += wa * h0.x + wb * hb.x + wc * hc.x + wd * hd.x;
        accy += wa * h0.y + wb * hb.y + wc * hc.y + wd * hd.y;
    }
    for (; i < end; ++i) {
        int s = csr_src[i];
        float2 w0 = w1v[i];
        float2 ha = __half22float2(((const __half2*)(h1 + (size_t)s * 128))[lane]);
        float wa = head ? w0.y : w0.x;
        den += wa;
        accx += wa * ha.x; accy += wa * ha.y;
    }
    float inv = 1.f / (den + GAT_EPS);
    accx *= inv; accy *= inv;
    int c0 = lane * 2;
    float ox = accx + b1[c0], oy = accy + b1[c0 + 1];
    ox = (ox > 0.f) ? ox : expm1f(ox);   // ELU
    oy = (oy > 0.f) ? oy : expm1f(oy);
    rows[wv][c0] = ox;
    rows[wv][c0 + 1] = oy;
    // rows[wv] written & read by the same wave — no barrier needed
    int j = lane & 15, q = lane >> 4;
    const float* r = rows[wv];
    const float* wt = &w2t[j * 132];
    int k0 = q * 32;
    float acc2 = 0.f;
#pragma unroll
    for (int kk = 0; kk < 32; kk += 4) {
        float4 rv = *(const float4*)(r + k0 + kk);
        float4 w4 = *(const float4*)(wt + k0 + kk);
        acc2 += rv.x * w4.x + rv.y * w4.y + rv.z * w4.z + rv.w * w4.w;
    }
    acc2 += __shfl_xor(acc2, 16, 64);
    acc2 += __shfl_xor(acc2, 32, 64);
    if (lane < 16) {
        h2[(size_t)d * 16 + j] = acc2;
        float ps = acc2 * att_src2[j];
        float pd = acc2 * att_dst2[j];
#pragma unroll
        for (int off = 8; off >= 1; off >>= 1) {
            ps += __shfl_xor(ps, off, 64);
            pd += __shfl_xor(pd, off, 64);
        }
        if (lane == 0) { as2[d] = ps; ad2[d] = pd; }
    }
}

// ---------------- Layer 2 aggregation + bias + softmax: one wave per node ----------------

__global__ __launch_bounds__(256) void k_agg2(
    const int* __restrict__ row_start, const int* __restrict__ csr_src,
    const float* __restrict__ h2, const float* __restrict__ as2,
    const float* __restrict__ ad2, const float* __restrict__ b2,
    float* __restrict__ out) {
    int t = threadIdx.x;
    int wv = t >> 6, lane = t & 63;
    int d = blockIdx.x * 4 + wv;
    int row = row_start[d], end = row_start[d + 1];
    float ad = ad2[d];
    int c = lane & 15, q = lane >> 4;
    float den = 0.f, acc = 0.f;
    for (int base = row; base < end; base += 64) {
        int idx = base + lane;
        float w = 0.f; int s = 0;
        if (idx < end) {
            s = csr_src[idx];
            float e = as2[s] + ad;
            e = (e >= 0.f) ? e : NEG_SLOPE * e;
            w = expf(e);
        }
        den += w;
        int m = end - base; if (m > 64) m = 64;
        for (int jj = 0; jj < m; jj += 4) {
            float wj = __shfl(w, jj + q, 64);
            int sj = __shfl(s, jj + q, 64);
            acc += wj * h2[(size_t)sj * 16 + c];
        }
    }
#pragma unroll
    for (int off = 32; off >= 1; off >>= 1) den += __shfl_xor(den, off, 64);
    acc += __shfl_xor(acc, 16, 64);
    acc += __shfl_xor(acc, 32, 64);
    float v = acc / (den + GAT_EPS) + b2[c];
    float mmax = v;
#pragma unroll
    for (int off = 8; off >= 1; off >>= 1) mmax = fmaxf(mmax, __shfl_xor(mmax, off, 16));
    float ex = expf(v - mmax);
    float sum = ex;
#pragma unroll
    for (int off = 8; off >= 1; off >>= 1) sum += __shfl_xor(sum, off, 16);
    if (lane < 16) out[(size_t)d * 16 + c] = ex / sum;
}

// ---------------- launch ----------------

extern "C" void kernel_launch(void* const* d_in, const int* in_sizes, int n_in,
                              void* d_out, int out_size, void* d_ws, size_t ws_size,
                              hipStream_t stream) {
    const float* x        = (const float*)d_in[0];
    const float* W1       = (const float*)d_in[1];
    const float* att_src1 = (const float*)d_in[2];
    const float* att_dst1 = (const float*)d_in[3];
    const float* b1       = (const float*)d_in[4];
    const float* W2       = (const float*)d_in[5];
    const float* att_src2 = (const float*)d_in[6];
    const float* att_dst2 = (const float*)d_in[7];
    const float* b2       = (const float*)d_in[8];
    const int*   ei       = (const int*)d_in[9];   // [2, E]: src row then dst row

    char* p = (char*)d_ws;
    auto alloc = [&](size_t bytes) {
        char* r = p;
        p += (bytes + 255) & ~(size_t)255;
        return r;
    };
    __half* h1     = (__half*)alloc(sizeof(__half) * (size_t)N_NODES * 128);
    float* h2      = (float*)alloc(sizeof(float) * (size_t)N_NODES * 16);
    float* a_src   = (float*)alloc(sizeof(float) * N_NODES * 2);
    float* a_dst   = (float*)alloc(sizeof(float) * N_NODES * 2);
    float* as2     = (float*)alloc(sizeof(float) * N_NODES);
    float* ad2     = (float*)alloc(sizeof(float) * N_NODES);
    int* cnt       = (int*)alloc(sizeof(int) * N_NODES * 2);  // cnt | fill, one memset
    int* fill      = cnt + N_NODES;
    int* row_start = (int*)alloc(sizeof(int) * (N_NODES + 1));
    int* csr_src   = (int*)alloc(sizeof(int) * N_EDGES);
    float* w1_csr  = (float*)alloc(sizeof(float) * (size_t)N_EDGES * 2);

    (void)hipMemsetAsync(cnt, 0, sizeof(int) * N_NODES * 2, stream);
    k_gemm1c<<<(N_NODES + 31) / 32, 256, 0, stream>>>(x, W1, att_src1, att_dst1, h1, a_src, a_dst, ei, cnt);
    k_scan<<<1, 1024, 0, stream>>>(cnt, row_start);
    k_scatter_w<<<(N_EDGES + 255) / 256, 256, 0, stream>>>(ei, row_start, fill, csr_src, a_src, a_dst, w1_csr);
    k_agg1f<<<N_NODES / 4, 256, 0, stream>>>(row_start, csr_src, h1, w1_csr, b1, W2, att_src2, att_dst2, h2, as2, ad2);
    k_agg2<<<N_NODES / 4, 256, 0, stream>>>(row_start, csr_src, h2, as2, ad2, b2, (float*)d_out);
}

// Round 7
// 408.067 us; speedup vs baseline: 1.3973x; 1.0829x over previous
//
#include <hip/hip_runtime.h>
#include <hip/hip_fp16.h>
#include <cstdint>
#include <cstddef>

#define N_NODES 50000
#define N_EDGES 1600000
#define NEG_SLOPE 0.2f
#define GAT_EPS 1e-16f

// ---------------- single-block exclusive scan, 4 elems/thread ----------------

__global__ void k_scan(const int* __restrict__ cnt, int* __restrict__ row_start) {
    __shared__ int wsum[16];
    __shared__ int wpre[16];
    __shared__ int total;
    __shared__ int chunk_base;
    int t = threadIdx.x;
    int lane = t & 63, wid = t >> 6;
    if (t == 0) chunk_base = 0;
    __syncthreads();
    for (int base = 0; base < N_NODES; base += 4096) {
        int i0 = base + t * 4;
        int v0 = (i0 + 0 < N_NODES) ? cnt[i0 + 0] : 0;
        int v1 = (i0 + 1 < N_NODES) ? cnt[i0 + 1] : 0;
        int v2 = (i0 + 2 < N_NODES) ? cnt[i0 + 2] : 0;
        int v3 = (i0 + 3 < N_NODES) ? cnt[i0 + 3] : 0;
        int s0 = v0, s1 = s0 + v1, s2 = s1 + v2, s3 = s2 + v3;
        int x = s3;
#pragma unroll
        for (int off = 1; off < 64; off <<= 1) {
            int y = __shfl_up(x, off, 64);
            if (lane >= off) x += y;
        }
        if (lane == 63) wsum[wid] = x;
        __syncthreads();
        if (t < 16) {
            int w = wsum[t];
            int xx = w;
#pragma unroll
            for (int off = 1; off < 16; off <<= 1) {
                int y = __shfl_up(xx, off, 16);
                if (t >= off) xx += y;
            }
            wpre[t] = xx - w;
            if (t == 15) total = xx;
        }
        __syncthreads();
        int excl = chunk_base + wpre[wid] + (x - s3);
        if (i0 + 3 < N_NODES) {
            ((int4*)row_start)[i0 >> 2] = make_int4(excl, excl + s0, excl + s1, excl + s2);
        } else {
            if (i0 + 0 < N_NODES) row_start[i0 + 0] = excl;
            if (i0 + 1 < N_NODES) row_start[i0 + 1] = excl + s0;
            if (i0 + 2 < N_NODES) row_start[i0 + 2] = excl + s1;
        }
        __syncthreads();
        if (t == 0) chunk_base += total;
        __syncthreads();
    }
    if (t == 0) row_start[N_NODES] = chunk_base;
}

// scatter + layer-1 edge weights
__global__ void k_scatter_w(const int* __restrict__ ei, const int* __restrict__ row_start,
                            int* __restrict__ fill, int* __restrict__ csr_src,
                            const float* __restrict__ a_src1, const float* __restrict__ a_dst1,
                            float* __restrict__ w1_csr) {
    int i = blockIdx.x * blockDim.x + threadIdx.x;
    if (i >= N_EDGES) return;
    int s = ei[i];
    int d = ei[N_EDGES + i];
    int pos = atomicAdd(&fill[d], 1);
    int slot = row_start[d] + pos;
    csr_src[slot] = s;
    float2 as = ((const float2*)a_src1)[s];
    float2 ad = ((const float2*)a_dst1)[d];
    float e0 = as.x + ad.x; e0 = (e0 >= 0.f) ? e0 : NEG_SLOPE * e0;
    float e1 = as.y + ad.y; e1 = (e1 >= 0.f) ? e1 : NEG_SLOPE * e1;
    ((float2*)w1_csr)[slot] = make_float2(expf(e0), expf(e1));
}

// ---------------- Layer 1 GEMM (fp16 out) + attention scalars + fused edge count ----------------
// 4x4 register tile per thread: 8 ds_read_b128 per 64 FMAs.

__global__ __launch_bounds__(256) void k_gemm1c(
    const float* __restrict__ x, const float* __restrict__ W1,
    const float* __restrict__ att_src, const float* __restrict__ att_dst,
    __half* __restrict__ h1, float* __restrict__ a_src, float* __restrict__ a_dst,
    const int* __restrict__ ei, int* __restrict__ cnt) {
    __shared__ float wl[128 * 128];
    __shared__ float xl[32 * 128];
    int t = threadIdx.x;
    int node0 = blockIdx.x * 32;
    // fused edge counting FIRST: fire-and-forget atomics overlap staging + compute
    {
        int e0 = blockIdx.x * 1024;
        int e1 = e0 + 1024; if (e1 > N_EDGES) e1 = N_EDGES;
        for (int e = e0 + t; e < e1; e += 256)
            atomicAdd(&cnt[ei[N_EDGES + e]], 1);
    }
    {
        const float4* Wv = (const float4*)W1;
        float4* wlv = (float4*)wl;
        for (int j = t; j < 128 * 128 / 4; j += 256) wlv[j] = Wv[j];
    }
    {
        float4* xlv = (float4*)xl;
        for (int j = t; j < 32 * 128 / 4; j += 256) {
            int n = j >> 5;
            int rem = j & 31;
            int gn = node0 + n;
            float4 v = make_float4(0.f, 0.f, 0.f, 0.f);
            if (gn < N_NODES) v = ((const float4*)x)[(size_t)gn * 32 + rem];
            xlv[j] = v;
        }
    }
    __syncthreads();
    int c0 = (t & 31) * 4;     // 4 output channels
    int n0 = (t >> 5) * 4;     // 4 block-local nodes
    float4 acc[4];
#pragma unroll
    for (int i = 0; i < 4; ++i) acc[i] = make_float4(0.f, 0.f, 0.f, 0.f);
    for (int k0 = 0; k0 < 128; k0 += 4) {
        float4 xr[4], wr[4];
#pragma unroll
        for (int i = 0; i < 4; ++i) xr[i] = *(const float4*)(xl + (n0 + i) * 128 + k0);
#pragma unroll
        for (int j = 0; j < 4; ++j) wr[j] = *(const float4*)(wl + (k0 + j) * 128 + c0);
#pragma unroll
        for (int i = 0; i < 4; ++i) {
#pragma unroll
            for (int j = 0; j < 4; ++j) {
                float s = (j == 0) ? xr[i].x : (j == 1) ? xr[i].y : (j == 2) ? xr[i].z : xr[i].w;
                acc[i].x += s * wr[j].x;
                acc[i].y += s * wr[j].y;
                acc[i].z += s * wr[j].z;
                acc[i].w += s * wr[j].w;
            }
        }
    }
    // epilogue: h1 (fp16) + per-(node,head) attention scalars
    float4 asv = ((const float4*)att_src)[t & 31];
    float4 adv = ((const float4*)att_dst)[t & 31];
    int lane = t & 63;
    int head = (c0 >= 64) ? 1 : 0;
#pragma unroll
    for (int i = 0; i < 4; ++i) {
        int gn = node0 + n0 + i;
        float4 h = acc[i];
        float ps = h.x * asv.x + h.y * asv.y + h.z * asv.z + h.w * asv.w;
        float pd = h.x * adv.x + h.y * adv.y + h.z * adv.z + h.w * adv.w;
#pragma unroll
        for (int off = 8; off >= 1; off >>= 1) {
            ps += __shfl_xor(ps, off, 64);
            pd += __shfl_xor(pd, off, 64);
        }
        if (gn < N_NODES) {
            __half2 p0 = __floats2half2_rn(h.x, h.y);
            __half2 p1 = __floats2half2_rn(h.z, h.w);
            *(__half2*)(h1 + (size_t)gn * 128 + c0) = p0;
            *(__half2*)(h1 + (size_t)gn * 128 + c0 + 2) = p1;
            if ((lane & 15) == 0) {
                a_src[gn * 2 + head] = ps;
                a_dst[gn * 2 + head] = pd;
            }
        }
    }
}

// ---------------- Layer 1 aggregation + ELU + fused layer-2 GEMM ----------------
// One wave per destination node; lane owns channels 2*lane, 2*lane+1.
// Weights are broadcast to all lanes, so every lane accumulates the full
// softmax denominator for its head as a byproduct.

__global__ __launch_bounds__(256) void k_agg1f(
    const int* __restrict__ row_start, const int* __restrict__ csr_src,
    const __half* __restrict__ h1, const float* __restrict__ w1_csr,
    const float* __restrict__ b1, const float* __restrict__ W2,
    const float* __restrict__ att_src2, const float* __restrict__ att_dst2,
    float* __restrict__ h2, float* __restrict__ as2, float* __restrict__ ad2) {
    __shared__ float w2t[16 * 132];     // W2^T, row padded to 132
    __shared__ float rows[4][128];
    int t = threadIdx.x;
    for (int i = t; i < 2048; i += 256) {
        int k = i >> 4, j = i & 15;
        w2t[j * 132 + k] = W2[i];
    }
    __syncthreads();   // only barrier: staging done before any wave needs w2t
    int wv = t >> 6, lane = t & 63;
    int d = blockIdx.x * 4 + wv;
    int row = row_start[d], end = row_start[d + 1];
    const float2* w1v = (const float2*)w1_csr;
    int head = lane >> 5;
    float den = 0.f, accx = 0.f, accy = 0.f;
    int i = row;
    for (; i + 4 <= end; i += 4) {
        int s0 = csr_src[i], s1 = csr_src[i + 1], s2 = csr_src[i + 2], s3 = csr_src[i + 3];
        float2 w0 = w1v[i], w1e = w1v[i + 1], w2e = w1v[i + 2], w3e = w1v[i + 3];
        float2 h0 = __half22float2(((const __half2*)(h1 + (size_t)s0 * 128))[lane]);
        float2 hb = __half22float2(((const __half2*)(h1 + (size_t)s1 * 128))[lane]);
        float2 hc = __half22float2(((const __half2*)(h1 + (size_t)s2 * 128))[lane]);
        float2 hd = __half22float2(((const __half2*)(h1 + (size_t)s3 * 128))[lane]);
        float wa = head ? w0.y : w0.x;
        float wb = head ? w1e.y : w1e.x;
        float wc = head ? w2e.y : w2e.x;
        float wd = head ? w3e.y : w3e.x;
        den += (wa + wb) + (wc + wd);
        accx += wa * h0.x + wb * hb.x + wc * hc.x + wd * hd.x;
        accy += wa * h0.y + wb * hb.y + wc * hc.y + wd * hd.y;
    }
    for (; i < end; ++i) {
        int s = csr_src[i];
        float2 w0 = w1v[i];
        float2 ha = __half22float2(((const __half2*)(h1 + (size_t)s * 128))[lane]);
        float wa = head ? w0.y : w0.x;
        den += wa;
        accx += wa * ha.x; accy += wa * ha.y;
    }
    float inv = 1.f / (den + GAT_EPS);
    accx *= inv; accy *= inv;
    int c0 = lane * 2;
    float ox = accx + b1[c0], oy = accy + b1[c0 + 1];
    ox = (ox > 0.f) ? ox : expm1f(ox);   // ELU
    oy = (oy > 0.f) ? oy : expm1f(oy);
    rows[wv][c0] = ox;
    rows[wv][c0 + 1] = oy;
    // rows[wv] written & read by the same wave — no barrier needed
    int j = lane & 15, q = lane >> 4;
    const float* r = rows[wv];
    const float* wt = &w2t[j * 132];
    int k0 = q * 32;
    float acc2 = 0.f;
#pragma unroll
    for (int kk = 0; kk < 32; kk += 4) {
        float4 rv = *(const float4*)(r + k0 + kk);
        float4 w4 = *(const float4*)(wt + k0 + kk);
        acc2 += rv.x * w4.x + rv.y * w4.y + rv.z * w4.z + rv.w * w4.w;
    }
    acc2 += __shfl_xor(acc2, 16, 64);
    acc2 += __shfl_xor(acc2, 32, 64);
    if (lane < 16) {
        h2[(size_t)d * 16 + j] = acc2;
        float ps = acc2 * att_src2[j];
        float pd = acc2 * att_dst2[j];
#pragma unroll
        for (int off = 8; off >= 1; off >>= 1) {
            ps += __shfl_xor(ps, off, 64);
            pd += __shfl_xor(pd, off, 64);
        }
        if (lane == 0) { as2[d] = ps; ad2[d] = pd; }
    }
}

// ---------------- Layer 2 aggregation + bias + softmax: one wave per node ----------------

__global__ __launch_bounds__(256) void k_agg2(
    const int* __restrict__ row_start, const int* __restrict__ csr_src,
    const float* __restrict__ h2, const float* __restrict__ as2,
    const float* __restrict__ ad2, const float* __restrict__ b2,
    float* __restrict__ out) {
    int t = threadIdx.x;
    int wv = t >> 6, lane = t & 63;
    int d = blockIdx.x * 4 + wv;
    int row = row_start[d], end = row_start[d + 1];
    float ad = ad2[d];
    int c = lane & 15, q = lane >> 4;
    float den = 0.f, acc = 0.f;
    for (int base = row; base < end; base += 64) {
        int idx = base + lane;
        float w = 0.f; int s = 0;
        if (idx < end) {
            s = csr_src[idx];
            float e = as2[s] + ad;
            e = (e >= 0.f) ? e : NEG_SLOPE * e;
            w = expf(e);
        }
        den += w;
        int m = end - base; if (m > 64) m = 64;
        for (int jj = 0; jj < m; jj += 4) {
            float wj = __shfl(w, jj + q, 64);
            int sj = __shfl(s, jj + q, 64);
            acc += wj * h2[(size_t)sj * 16 + c];
        }
    }
#pragma unroll
    for (int off = 32; off >= 1; off >>= 1) den += __shfl_xor(den, off, 64);
    acc += __shfl_xor(acc, 16, 64);
    acc += __shfl_xor(acc, 32, 64);
    float v = acc / (den + GAT_EPS) + b2[c];
    float mmax = v;
#pragma unroll
    for (int off = 8; off >= 1; off >>= 1) mmax = fmaxf(mmax, __shfl_xor(mmax, off, 16));
    float ex = expf(v - mmax);
    float sum = ex;
#pragma unroll
    for (int off = 8; off >= 1; off >>= 1) sum += __shfl_xor(sum, off, 16);
    if (lane < 16) out[(size_t)d * 16 + c] = ex / sum;
}

// ---------------- launch ----------------

extern "C" void kernel_launch(void* const* d_in, const int* in_sizes, int n_in,
                              void* d_out, int out_size, void* d_ws, size_t ws_size,
                              hipStream_t stream) {
    const float* x        = (const float*)d_in[0];
    const float* W1       = (const float*)d_in[1];
    const float* att_src1 = (const float*)d_in[2];
    const float* att_dst1 = (const float*)d_in[3];
    const float* b1       = (const float*)d_in[4];
    const float* W2       = (const float*)d_in[5];
    const float* att_src2 = (const float*)d_in[6];
    const float* att_dst2 = (const float*)d_in[7];
    const float* b2       = (const float*)d_in[8];
    const int*   ei       = (const int*)d_in[9];   // [2, E]: src row then dst row

    char* p = (char*)d_ws;
    auto alloc = [&](size_t bytes) {
        char* r = p;
        p += (bytes + 255) & ~(size_t)255;
        return r;
    };
    __half* h1     = (__half*)alloc(sizeof(__half) * (size_t)N_NODES * 128);
    float* h2      = (float*)alloc(sizeof(float) * (size_t)N_NODES * 16);
    float* a_src   = (float*)alloc(sizeof(float) * N_NODES * 2);
    float* a_dst   = (float*)alloc(sizeof(float) * N_NODES * 2);
    float* as2     = (float*)alloc(sizeof(float) * N_NODES);
    float* ad2     = (float*)alloc(sizeof(float) * N_NODES);
    int* cnt       = (int*)alloc(sizeof(int) * N_NODES * 2);  // cnt | fill, one memset
    int* fill      = cnt + N_NODES;
    int* row_start = (int*)alloc(sizeof(int) * (N_NODES + 1));
    int* csr_src   = (int*)alloc(sizeof(int) * N_EDGES);
    float* w1_csr  = (float*)alloc(sizeof(float) * (size_t)N_EDGES * 2);

    (void)hipMemsetAsync(cnt, 0, sizeof(int) * N_NODES * 2, stream);
    k_gemm1c<<<(N_NODES + 31) / 32, 256, 0, stream>>>(x, W1, att_src1, att_dst1, h1, a_src, a_dst, ei, cnt);
    k_scan<<<1, 1024, 0, stream>>>(cnt, row_start);
    k_scatter_w<<<(N_EDGES + 255) / 256, 256, 0, stream>>>(ei, row_start, fill, csr_src, a_src, a_dst, w1_csr);
    k_agg1f<<<N_NODES / 4, 256, 0, stream>>>(row_start, csr_src, h1, w1_csr, b1, W2, att_src2, att_dst2, h2, as2, ad2);
    k_agg2<<<N_NODES / 4, 256, 0, stream>>>(row_start, csr_src, h2, as2, ad2, b2, (float*)d_out);
}

// Round 8
// 389.000 us; speedup vs baseline: 1.4658x; 1.0490x over previous
//
#include <hip/hip_runtime.h>
#include <hip/hip_fp16.h>
#include <cstdint>
#include <cstddef>

#define N_NODES 50000
#define N_EDGES 1600000
#define NEG_SLOPE 0.2f
#define GAT_EPS 1e-16f

// ---------------- single-block exclusive scan, 4 elems/thread ----------------

__global__ void k_scan(const int* __restrict__ cnt, int* __restrict__ row_start) {
    __shared__ int wsum[16];
    __shared__ int wpre[16];
    __shared__ int total;
    __shared__ int chunk_base;
    int t = threadIdx.x;
    int lane = t & 63, wid = t >> 6;
    if (t == 0) chunk_base = 0;
    __syncthreads();
    for (int base = 0; base < N_NODES; base += 4096) {
        int i0 = base + t * 4;
        int v0 = (i0 + 0 < N_NODES) ? cnt[i0 + 0] : 0;
        int v1 = (i0 + 1 < N_NODES) ? cnt[i0 + 1] : 0;
        int v2 = (i0 + 2 < N_NODES) ? cnt[i0 + 2] : 0;
        int v3 = (i0 + 3 < N_NODES) ? cnt[i0 + 3] : 0;
        int s0 = v0, s1 = s0 + v1, s2 = s1 + v2, s3 = s2 + v3;
        int x = s3;
#pragma unroll
        for (int off = 1; off < 64; off <<= 1) {
            int y = __shfl_up(x, off, 64);
            if (lane >= off) x += y;
        }
        if (lane == 63) wsum[wid] = x;
        __syncthreads();
        if (t < 16) {
            int w = wsum[t];
            int xx = w;
#pragma unroll
            for (int off = 1; off < 16; off <<= 1) {
                int y = __shfl_up(xx, off, 16);
                if (t >= off) xx += y;
            }
            wpre[t] = xx - w;
            if (t == 15) total = xx;
        }
        __syncthreads();
        int excl = chunk_base + wpre[wid] + (x - s3);
        if (i0 + 3 < N_NODES) {
            ((int4*)row_start)[i0 >> 2] = make_int4(excl, excl + s0, excl + s1, excl + s2);
        } else {
            if (i0 + 0 < N_NODES) row_start[i0 + 0] = excl;
            if (i0 + 1 < N_NODES) row_start[i0 + 1] = excl + s0;
            if (i0 + 2 < N_NODES) row_start[i0 + 2] = excl + s1;
        }
        __syncthreads();
        if (t == 0) chunk_base += total;
        __syncthreads();
    }
    if (t == 0) row_start[N_NODES] = chunk_base;
}

// scatter + layer-1 edge weights, packed {src,w0,w1,pad} 16B entry.
// Dst-bucketed pass: only edges with d in [lo,hi) are scattered, confining the
// dirty write region so L2 retains lines until all 4 entry-writes arrive.
__global__ void k_scatter_w(const int* __restrict__ ei, const int* __restrict__ row_start,
                            int* __restrict__ fill, int4* __restrict__ csr,
                            const float* __restrict__ a_src1, const float* __restrict__ a_dst1,
                            int lo, int hi) {
    int i = blockIdx.x * blockDim.x + threadIdx.x;
    if (i >= N_EDGES) return;
    int d = ei[N_EDGES + i];
    if (d < lo || d >= hi) return;
    int s = ei[i];
    int pos = atomicAdd(&fill[d], 1);
    int slot = row_start[d] + pos;
    float2 as = ((const float2*)a_src1)[s];
    float2 ad = ((const float2*)a_dst1)[d];
    float e0 = as.x + ad.x; e0 = (e0 >= 0.f) ? e0 : NEG_SLOPE * e0;
    float e1 = as.y + ad.y; e1 = (e1 >= 0.f) ? e1 : NEG_SLOPE * e1;
    csr[slot] = make_int4(s, __float_as_int(expf(e0)), __float_as_int(expf(e1)), 0);
}

// ---------------- Layer 1 GEMM (fp16 out) + attention scalars + fused edge count ----------------
// 4x4 register tile per thread: 8 ds_read_b128 per 64 FMAs.

__global__ __launch_bounds__(256) void k_gemm1c(
    const float* __restrict__ x, const float* __restrict__ W1,
    const float* __restrict__ att_src, const float* __restrict__ att_dst,
    __half* __restrict__ h1, float* __restrict__ a_src, float* __restrict__ a_dst,
    const int* __restrict__ ei, int* __restrict__ cnt) {
    __shared__ float wl[128 * 128];
    __shared__ float xl[32 * 128];
    int t = threadIdx.x;
    int node0 = blockIdx.x * 32;
    // fused edge counting FIRST: fire-and-forget atomics overlap staging + compute
    {
        int e0 = blockIdx.x * 1024;
        int e1 = e0 + 1024; if (e1 > N_EDGES) e1 = N_EDGES;
        for (int e = e0 + t; e < e1; e += 256)
            atomicAdd(&cnt[ei[N_EDGES + e]], 1);
    }
    {
        const float4* Wv = (const float4*)W1;
        float4* wlv = (float4*)wl;
        for (int j = t; j < 128 * 128 / 4; j += 256) wlv[j] = Wv[j];
    }
    {
        float4* xlv = (float4*)xl;
        for (int j = t; j < 32 * 128 / 4; j += 256) {
            int n = j >> 5;
            int rem = j & 31;
            int gn = node0 + n;
            float4 v = make_float4(0.f, 0.f, 0.f, 0.f);
            if (gn < N_NODES) v = ((const float4*)x)[(size_t)gn * 32 + rem];
            xlv[j] = v;
        }
    }
    __syncthreads();
    int c0 = (t & 31) * 4;     // 4 output channels
    int n0 = (t >> 5) * 4;     // 4 block-local nodes
    float4 acc[4];
#pragma unroll
    for (int i = 0; i < 4; ++i) acc[i] = make_float4(0.f, 0.f, 0.f, 0.f);
    for (int k0 = 0; k0 < 128; k0 += 4) {
        float4 xr[4], wr[4];
#pragma unroll
        for (int i = 0; i < 4; ++i) xr[i] = *(const float4*)(xl + (n0 + i) * 128 + k0);
#pragma unroll
        for (int j = 0; j < 4; ++j) wr[j] = *(const float4*)(wl + (k0 + j) * 128 + c0);
#pragma unroll
        for (int i = 0; i < 4; ++i) {
#pragma unroll
            for (int j = 0; j < 4; ++j) {
                float s = (j == 0) ? xr[i].x : (j == 1) ? xr[i].y : (j == 2) ? xr[i].z : xr[i].w;
                acc[i].x += s * wr[j].x;
                acc[i].y += s * wr[j].y;
                acc[i].z += s * wr[j].z;
                acc[i].w += s * wr[j].w;
            }
        }
    }
    // epilogue: h1 (fp16) + per-(node,head) attention scalars
    float4 asv = ((const float4*)att_src)[t & 31];
    float4 adv = ((const float4*)att_dst)[t & 31];
    int lane = t & 63;
    int head = (c0 >= 64) ? 1 : 0;
#pragma unroll
    for (int i = 0; i < 4; ++i) {
        int gn = node0 + n0 + i;
        float4 h = acc[i];
        float ps = h.x * asv.x + h.y * asv.y + h.z * asv.z + h.w * asv.w;
        float pd = h.x * adv.x + h.y * adv.y + h.z * adv.z + h.w * adv.w;
#pragma unroll
        for (int off = 8; off >= 1; off >>= 1) {
            ps += __shfl_xor(ps, off, 64);
            pd += __shfl_xor(pd, off, 64);
        }
        if (gn < N_NODES) {
            __half2 p0 = __floats2half2_rn(h.x, h.y);
            __half2 p1 = __floats2half2_rn(h.z, h.w);
            *(__half2*)(h1 + (size_t)gn * 128 + c0) = p0;
            *(__half2*)(h1 + (size_t)gn * 128 + c0 + 2) = p1;
            if ((lane & 15) == 0) {
                a_src[gn * 2 + head] = ps;
                a_dst[gn * 2 + head] = pd;
            }
        }
    }
}

// ---------------- Layer 1 aggregation + ELU + fused layer-2 GEMM ----------------
// One wave per destination node, pair-scheme: lanes 0..31 process even edges,
// lanes 32..63 odd edges; each lane covers 4 channels (c0 = 4*(lane&31)).
// Cross-half combine via shfl_xor(32) at the end.

__global__ __launch_bounds__(256) void k_agg1f(
    const int* __restrict__ row_start, const int4* __restrict__ csr,
    const __half* __restrict__ h1, const float* __restrict__ b1,
    const float* __restrict__ W2,
    const float* __restrict__ att_src2, const float* __restrict__ att_dst2,
    float* __restrict__ h2, float* __restrict__ as2, float* __restrict__ ad2) {
    __shared__ float w2t[16 * 132];     // W2^T, row padded to 132
    __shared__ float rows[4][128];
    int t = threadIdx.x;
    for (int i = t; i < 2048; i += 256) {
        int k = i >> 4, j = i & 15;
        w2t[j * 132 + k] = W2[i];
    }
    __syncthreads();   // only barrier: staging done before any wave needs w2t
    int wv = t >> 6, lane = t & 63;
    int d = blockIdx.x * 4 + wv;
    int row = row_start[d], end = row_start[d + 1];
    int half = lane >> 5;      // 0: even edges, 1: odd edges
    int L = lane & 31;
    int c0 = L * 4;            // 4 channels
    int head = (L >= 16) ? 1 : 0;
    float den = 0.f;
    float4 acc = make_float4(0.f, 0.f, 0.f, 0.f);
    int i = row;
    for (; i + 8 <= end; i += 8) {
#pragma unroll
        for (int p = 0; p < 4; ++p) {
            int idx = i + 2 * p + half;
            int4 e4 = csr[idx];
            int s = e4.x;
            float we = head ? __int_as_float(e4.z) : __int_as_float(e4.y);
            uint2 u = *(const uint2*)(h1 + (size_t)s * 128 + c0);
            __half2 p0 = *(__half2*)&u.x;
            __half2 p1 = *(__half2*)&u.y;
            float2 f0 = __half22float2(p0);
            float2 f1 = __half22float2(p1);
            den += we;
            acc.x += we * f0.x; acc.y += we * f0.y;
            acc.z += we * f1.x; acc.w += we * f1.y;
        }
    }
    for (; i < end; i += 2) {
        int idx = i + half;
        bool ok = idx < end;
        int idxc = ok ? idx : i;
        int4 e4 = csr[idxc];
        int s = e4.x;
        float we = head ? __int_as_float(e4.z) : __int_as_float(e4.y);
        if (!ok) we = 0.f;
        uint2 u = *(const uint2*)(h1 + (size_t)s * 128 + c0);
        __half2 p0 = *(__half2*)&u.x;
        __half2 p1 = *(__half2*)&u.y;
        float2 f0 = __half22float2(p0);
        float2 f1 = __half22float2(p1);
        den += we;
        acc.x += we * f0.x; acc.y += we * f0.y;
        acc.z += we * f1.x; acc.w += we * f1.y;
    }
    // combine even/odd halves (partner lane has same channels & head)
    den += __shfl_xor(den, 32, 64);
    acc.x += __shfl_xor(acc.x, 32, 64);
    acc.y += __shfl_xor(acc.y, 32, 64);
    acc.z += __shfl_xor(acc.z, 32, 64);
    acc.w += __shfl_xor(acc.w, 32, 64);
    float inv = 1.f / (den + GAT_EPS);
    float4 bv = ((const float4*)b1)[L];
    float o0 = acc.x * inv + bv.x;
    float o1 = acc.y * inv + bv.y;
    float o2 = acc.z * inv + bv.z;
    float o3 = acc.w * inv + bv.w;
    o0 = (o0 > 0.f) ? o0 : expm1f(o0);   // ELU
    o1 = (o1 > 0.f) ? o1 : expm1f(o1);
    o2 = (o2 > 0.f) ? o2 : expm1f(o2);
    o3 = (o3 > 0.f) ? o3 : expm1f(o3);
    if (half == 0) *(float4*)(&rows[wv][c0]) = make_float4(o0, o1, o2, o3);
    // rows[wv] written & read by the same wave — no barrier needed
    int j = lane & 15, q = lane >> 4;
    const float* r = rows[wv];
    const float* wt = &w2t[j * 132];
    int k0 = q * 32;
    float acc2 = 0.f;
#pragma unroll
    for (int kk = 0; kk < 32; kk += 4) {
        float4 rv = *(const float4*)(r + k0 + kk);
        float4 w4 = *(const float4*)(wt + k0 + kk);
        acc2 += rv.x * w4.x + rv.y * w4.y + rv.z * w4.z + rv.w * w4.w;
    }
    acc2 += __shfl_xor(acc2, 16, 64);
    acc2 += __shfl_xor(acc2, 32, 64);
    if (lane < 16) {
        h2[(size_t)d * 16 + j] = acc2;
        float ps = acc2 * att_src2[j];
        float pd = acc2 * att_dst2[j];
#pragma unroll
        for (int off = 8; off >= 1; off >>= 1) {
            ps += __shfl_xor(ps, off, 64);
            pd += __shfl_xor(pd, off, 64);
        }
        if (lane == 0) { as2[d] = ps; ad2[d] = pd; }
    }
}

// ---------------- Layer 2 aggregation + bias + softmax: one wave per node ----------------

__global__ __launch_bounds__(256) void k_agg2(
    const int* __restrict__ row_start, const int4* __restrict__ csr,
    const float* __restrict__ h2, const float* __restrict__ as2,
    const float* __restrict__ ad2, const float* __restrict__ b2,
    float* __restrict__ out) {
    int t = threadIdx.x;
    int wv = t >> 6, lane = t & 63;
    int d = blockIdx.x * 4 + wv;
    int row = row_start[d], end = row_start[d + 1];
    float ad = ad2[d];
    int c = lane & 15, q = lane >> 4;
    float den = 0.f, acc = 0.f;
    for (int base = row; base < end; base += 64) {
        int idx = base + lane;
        float w = 0.f; int s = 0;
        if (idx < end) {
            s = csr[idx].x;
            float e = as2[s] + ad;
            e = (e >= 0.f) ? e : NEG_SLOPE * e;
            w = expf(e);
        }
        den += w;
        int m = end - base; if (m > 64) m = 64;
        for (int jj = 0; jj < m; jj += 4) {
            float wj = __shfl(w, jj + q, 64);
            int sj = __shfl(s, jj + q, 64);
            acc += wj * h2[(size_t)sj * 16 + c];
        }
    }
#pragma unroll
    for (int off = 32; off >= 1; off >>= 1) den += __shfl_xor(den, off, 64);
    acc += __shfl_xor(acc, 16, 64);
    acc += __shfl_xor(acc, 32, 64);
    float v = acc / (den + GAT_EPS) + b2[c];
    float mmax = v;
#pragma unroll
    for (int off = 8; off >= 1; off >>= 1) mmax = fmaxf(mmax, __shfl_xor(mmax, off, 16));
    float ex = expf(v - mmax);
    float sum = ex;
#pragma unroll
    for (int off = 8; off >= 1; off >>= 1) sum += __shfl_xor(sum, off, 16);
    if (lane < 16) out[(size_t)d * 16 + c] = ex / sum;
}

// ---------------- launch ----------------

extern "C" void kernel_launch(void* const* d_in, const int* in_sizes, int n_in,
                              void* d_out, int out_size, void* d_ws, size_t ws_size,
                              hipStream_t stream) {
    const float* x        = (const float*)d_in[0];
    const float* W1       = (const float*)d_in[1];
    const float* att_src1 = (const float*)d_in[2];
    const float* att_dst1 = (const float*)d_in[3];
    const float* b1       = (const float*)d_in[4];
    const float* W2       = (const float*)d_in[5];
    const float* att_src2 = (const float*)d_in[6];
    const float* att_dst2 = (const float*)d_in[7];
    const float* b2       = (const float*)d_in[8];
    const int*   ei       = (const int*)d_in[9];   // [2, E]: src row then dst row

    char* p = (char*)d_ws;
    auto alloc = [&](size_t bytes) {
        char* r = p;
        p += (bytes + 255) & ~(size_t)255;
        return r;
    };
    __half* h1     = (__half*)alloc(sizeof(__half) * (size_t)N_NODES * 128);
    float* h2      = (float*)alloc(sizeof(float) * (size_t)N_NODES * 16);
    float* a_src   = (float*)alloc(sizeof(float) * N_NODES * 2);
    float* a_dst   = (float*)alloc(sizeof(float) * N_NODES * 2);
    float* as2     = (float*)alloc(sizeof(float) * N_NODES);
    float* ad2     = (float*)alloc(sizeof(float) * N_NODES);
    int* cnt       = (int*)alloc(sizeof(int) * N_NODES * 2);  // cnt | fill, one memset
    int* fill      = cnt + N_NODES;
    int* row_start = (int*)alloc(sizeof(int) * (N_NODES + 1));
    int4* csr      = (int4*)alloc(sizeof(int4) * (size_t)N_EDGES);

    (void)hipMemsetAsync(cnt, 0, sizeof(int) * N_NODES * 2, stream);
    k_gemm1c<<<(N_NODES + 31) / 32, 256, 0, stream>>>(x, W1, att_src1, att_dst1, h1, a_src, a_dst, ei, cnt);
    k_scan<<<1, 1024, 0, stream>>>(cnt, row_start);
    k_scatter_w<<<(N_EDGES + 255) / 256, 256, 0, stream>>>(ei, row_start, fill, csr, att_src1 ? a_src : a_src, a_dst, 0, 25000);
    k_scatter_w<<<(N_EDGES + 255) / 256, 256, 0, stream>>>(ei, row_start, fill, csr, a_src, a_dst, 25000, 50000);
    k_agg1f<<<N_NODES / 4, 256, 0, stream>>>(row_start, csr, h1, b1, W2, att_src2, att_dst2, h2, as2, ad2);
    k_agg2<<<N_NODES / 4, 256, 0, stream>>>(row_start, csr, h2, as2, ad2, b2, (float*)d_out);
}